// Round 1
// baseline (53.077 us; speedup 1.0000x reference)
//
#include <hip/hip_runtime.h>

// TrigoLinear: out[b,o] = sum_i w_out[o,i] * sin(x[b,i]*w_sin[o,i] + b_sin[o,i]) + b_out[o]
// B=2048, I=256, O=512. Compute-bound on v_sin (268M transcendentals).
//
// Layout: lanes = 64 consecutive b's; each wave owns 4 wave-uniform o's so all
// weight/bias reads are scalar (s_load) — keeps VALU+LDS pipes free for the
// 5-instruction sin chain. x is staged transposed in LDS, pre-scaled by 1/2pi
// so v_sin (revolution input) needs only mul+fma+fract.

#define B_SZ 2048
#define I_SZ 256
#define O_SZ 512
#define BTILE 64
#define ITILE 128
#define OBLOCK 16   // o's per block (4 waves x 4)
#define NOO 4       // o's per wave

static constexpr float kInv2Pi = 0.15915494309189535f;

__global__ __launch_bounds__(256, 4) void TrigoLinear_kernel(
    const float* __restrict__ x, const float* __restrict__ w,
    const float* __restrict__ bias, float* __restrict__ out) {
  // padded to 65 floats: write stride 65 -> 2-way bank alias (free),
  // read xT[i][lane] -> consecutive words (free)
  __shared__ float xT[ITILE][BTILE + 1];

  const int tid = threadIdx.x;
  const int lane = tid & 63;
  const int wave = __builtin_amdgcn_readfirstlane(tid >> 6);  // force SGPR

  const int btile = blockIdx.x & 31;   // 32 b-tiles
  const int oblock = blockIdx.x >> 5;  // 32 o-blocks
  const int b0 = btile * BTILE;
  const int o_base = oblock * OBLOCK + wave * NOO;  // wave-uniform

  float acc[NOO] = {0.f, 0.f, 0.f, 0.f};

  for (int it = 0; it < I_SZ / ITILE; ++it) {
    __syncthreads();
    // stage x[b0..b0+63][it*128 .. +127] transposed & pre-scaled by 1/2pi.
    // 8192 elems / 256 threads = 32 each; each wave reads one coalesced
    // 256B row segment per step.
#pragma unroll
    for (int k = 0; k < 32; ++k) {
      int e = tid + k * 256;
      int row = e >> 7;   // b offset within tile
      int col = e & 127;  // i offset within tile
      xT[col][row] = x[(b0 + row) * I_SZ + it * ITILE + col] * kInv2Pi;
    }
    __syncthreads();

#pragma unroll 4
    for (int i = 0; i < ITILE; ++i) {
      const float xs = xT[i][lane];  // 1 ds_read_b32, conflict-free
      const int ig = it * ITILE + i;
#pragma unroll
      for (int oo = 0; oo < NOO; ++oo) {
        const int o = o_base + oo;  // wave-uniform -> scalar loads below
        const float wov = w[o * (2 * I_SZ) + 2 * ig];      // weight[o][i][0]
        const float wsv = w[o * (2 * I_SZ) + 2 * ig + 1];  // weight[o][i][1]
        const float bsv = bias[o * (I_SZ + 1) + ig];       // bias[o][i]
        float t = xs * wsv;                          // rev units (xs pre-scaled)
        float rev = __builtin_fmaf(bsv, kInv2Pi, t); // inline-const 0.15915494
        float r = __builtin_amdgcn_fractf(rev);      // v_fract_f32
        float sv = __builtin_amdgcn_sinf(r);         // v_sin_f32 (revolutions)
        acc[oo] = __builtin_fmaf(sv, wov, acc[oo]);
      }
    }
  }

  const int b = b0 + lane;
#pragma unroll
  for (int oo = 0; oo < NOO; ++oo) {
    const int o = o_base + oo;
    const float bout = bias[o * (I_SZ + 1) + I_SZ];  // bias[o][I]
    out[b * O_SZ + o] = acc[oo] + bout;
  }
}

extern "C" void kernel_launch(void* const* d_in, const int* in_sizes, int n_in,
                              void* d_out, int out_size, void* d_ws, size_t ws_size,
                              hipStream_t stream) {
  const float* x = (const float*)d_in[0];     // (2048, 256) f32
  const float* w = (const float*)d_in[1];     // (512, 256, 2) f32
  const float* bias = (const float*)d_in[2];  // (512, 257) f32
  float* out = (float*)d_out;                 // (2048, 512) f32

  const int grid = (B_SZ / BTILE) * (O_SZ / OBLOCK);  // 32 * 32 = 1024
  TrigoLinear_kernel<<<dim3(grid), dim3(256), 0, stream>>>(x, w, bias, out);
}